// Round 1
// baseline (424.783 us; speedup 1.0000x reference)
//
#include <hip/hip_runtime.h>
#include <cstdint>
#include <cstddef>

// Problem constants (fixed by the reference)
constexpr int B_   = 2;
constexpr int NLR  = 8192;
constexpr int NHR  = 16384;
constexpr int CCH  = 32;    // feature channels
constexpr int NS   = 64;    // nsample
constexpr int TILE = 2048;  // hr points staged in LDS per iteration
constexpr int QPW  = 4;     // queries per wave
constexpr int QPB  = 16;    // queries per block (4 waves)
constexpr int THREADS = 256;

// xyz = (float)i * vox + off + 0.5f*vox, all ops round-to-nearest f32,
// no fma contraction — must match the JAX/np reference bit-for-bit so the
// d2 <= 1.0 boundary test never flips.
__device__ __forceinline__ float cvt_coord(int i, float vox, float off) {
    return __fadd_rn(__fadd_rn(__fmul_rn((float)i, vox), off), __fmul_rn(0.5f, vox));
}

extern "C" __global__ void __launch_bounds__(THREADS, 2)
bignn_grouper(const int* __restrict__ lr_idx, const int* __restrict__ hr_idx,
              const float* __restrict__ lr_feat, const float* __restrict__ hr_feat,
              const float* __restrict__ W1, const float* __restrict__ b1,
              const float* __restrict__ W2, const float* __restrict__ b2,
              float* __restrict__ out)
{
    __shared__ float4 tile[TILE];      // hr xyz, ascending index order
    __shared__ int lists[QPB][NS];     // per-query neighbor index lists

    const int tid  = threadIdx.x;
    const int wave = tid >> 6;
    const int lane = tid & 63;
    const int q0   = blockIdx.x * QPB;     // first global query id of block
    const int b    = q0 / NLR;             // whole block is in one batch (8192 % 16 == 0)
    const int* hbase = hr_idx + (size_t)b * NHR * 3;

    // --- query centers (wave-uniform) ---
    float cx[QPW], cy[QPW], cz[QPW];
    int cnt[QPW];
#pragma unroll
    for (int i = 0; i < QPW; ++i) {
        const int q = q0 + wave * QPW + i;
        const int* ip = lr_idx + (size_t)q * 3;   // (z,y,x)
        cx[i] = cvt_coord(ip[2], 0.4f,   0.0f);
        cy[i] = cvt_coord(ip[1], 0.4f, -40.0f);
        cz[i] = cvt_coord(ip[0], 1.0f,  -3.0f);
        cnt[i] = 0;
    }

    // --- ball query: tiled scan over hr points in ascending index order ---
    for (int t0 = 0; t0 < NHR; t0 += TILE) {
        __syncthreads();   // previous tile fully consumed
        // stage: thread t handles points {p*256 + t}; LDS write stride 16B -> conflict-free
#pragma unroll
        for (int p = 0; p < TILE / THREADS; ++p) {
            const int j = p * THREADS + tid;
            const int* ip = hbase + (size_t)(t0 + j) * 3;  // (z,y,x)
            float4 v;
            v.x = cvt_coord(ip[2], 0.05f,   0.0f);
            v.y = cvt_coord(ip[1], 0.05f, -40.0f);
            v.z = cvt_coord(ip[0], 0.1f,   -3.0f);
            v.w = 0.0f;
            tile[j] = v;
        }
        __syncthreads();

        if (cnt[0] < NS || cnt[1] < NS || cnt[2] < NS || cnt[3] < NS) {
            for (int j0 = 0; j0 < TILE; j0 += 64) {
                const float4 p = tile[j0 + lane];   // ds_read_b128, conflict-free
#pragma unroll
                for (int i = 0; i < QPW; ++i) {
                    if (cnt[i] >= NS) continue;     // uniform condition
                    const float dx = __fsub_rn(cx[i], p.x);
                    const float dy = __fsub_rn(cy[i], p.y);
                    const float dz = __fsub_rn(cz[i], p.z);
                    const float d2 = __fadd_rn(__fadd_rn(__fmul_rn(dx, dx),
                                                         __fmul_rn(dy, dy)),
                                               __fmul_rn(dz, dz));
                    const bool ok = d2 <= 1.0f;
                    const unsigned long long m = __ballot(ok);
                    if (m != 0ull) {
                        const int before = (int)__popcll(m & ((1ull << lane) - 1ull));
                        const int pos = cnt[i] + before;
                        if (ok && pos < NS)
                            lists[wave * QPW + i][pos] = t0 + j0 + lane;
                        cnt[i] += (int)__popcll(m);
                        if (cnt[i] > NS) cnt[i] = NS;
                    }
                }
            }
        }
    }

    // --- MLP + max-pool: lane = neighbor slot ---
#pragma unroll 1
    for (int i = 0; i < QPW; ++i) {
        const int q  = q0 + wave * QPW + i;
        const int c  = cnt[i];
        const int wl = wave * QPW + i;

        int nidx = 0;                       // c==0 -> point 0 (reference semantics)
        if (c > 0) {
            const int firstn = lists[wl][0];
            nidx = (lane < c) ? lists[wl][lane] : firstn;
        }

        // neighbor xyz (recompute from indices; exact same arithmetic)
        const int* ip = hbase + (size_t)nidx * 3;
        const float px = cvt_coord(ip[2], 0.05f,   0.0f);
        const float py = cvt_coord(ip[1], 0.05f, -40.0f);
        const float pz = cvt_coord(ip[0], 0.1f,   -3.0f);

        float g[3 + CCH];
        g[0] = __fsub_rn(px, cx[i]);        // rel = hr - lr
        g[1] = __fsub_rn(py, cy[i]);
        g[2] = __fsub_rn(pz, cz[i]);
        const float4* fp = reinterpret_cast<const float4*>(hr_feat + ((size_t)b * NHR + nidx) * CCH);
#pragma unroll
        for (int k = 0; k < CCH / 4; ++k) {
            const float4 v = fp[k];
            g[3 + 4 * k + 0] = v.x;
            g[3 + 4 * k + 1] = v.y;
            g[3 + 4 * k + 2] = v.z;
            g[3 + 4 * k + 3] = v.w;
        }

        // layer 1: 35 -> 32 (weights wave-uniform -> scalar loads)
        float h[32];
#pragma unroll
        for (int j = 0; j < 32; ++j) h[j] = b1[j];
#pragma unroll
        for (int k = 0; k < 35; ++k) {
            const float gk = g[k];
#pragma unroll
            for (int j = 0; j < 32; ++j)
                h[j] = fmaf(gk, W1[k * 32 + j], h[j]);
        }
#pragma unroll
        for (int j = 0; j < 32; ++j) h[j] = fmaxf(h[j], 0.0f);

        // layer 2: 32 -> 32
        float h2[32];
#pragma unroll
        for (int j = 0; j < 32; ++j) h2[j] = b2[j];
#pragma unroll
        for (int k = 0; k < 32; ++k) {
            const float hk = h[k];
#pragma unroll
            for (int j = 0; j < 32; ++j)
                h2[j] = fmaf(hk, W2[k * 32 + j], h2[j]);
        }
#pragma unroll
        for (int j = 0; j < 32; ++j) h2[j] = fmaxf(h2[j], 0.0f);

        // max over 64 neighbor slots: 6-step xor butterfly
#pragma unroll
        for (int s = 32; s >= 1; s >>= 1) {
#pragma unroll
            for (int j = 0; j < 32; ++j)
                h2[j] = fmaxf(h2[j], __shfl_xor(h2[j], s, 64));
        }

        // write: out[q] = [lr_feat(32) | pooled(32)]
        float* orow = out + (size_t)q * (2 * CCH);
        if (lane < CCH)
            orow[lane] = lr_feat[(size_t)q * CCH + lane];
        if (lane == 0) {
#pragma unroll
            for (int j = 0; j < 8; ++j) {
                float4 v;
                v.x = h2[4 * j + 0];
                v.y = h2[4 * j + 1];
                v.z = h2[4 * j + 2];
                v.w = h2[4 * j + 3];
                reinterpret_cast<float4*>(orow + CCH)[j] = v;
            }
        }
    }
}

extern "C" void kernel_launch(void* const* d_in, const int* in_sizes, int n_in,
                              void* d_out, int out_size, void* d_ws, size_t ws_size,
                              hipStream_t stream) {
    const int*   lr_idx  = (const int*)  d_in[0];
    const int*   hr_idx  = (const int*)  d_in[1];
    const float* lr_feat = (const float*)d_in[2];
    const float* hr_feat = (const float*)d_in[3];
    const float* W1      = (const float*)d_in[4];
    const float* b1      = (const float*)d_in[5];
    const float* W2      = (const float*)d_in[6];
    const float* b2      = (const float*)d_in[7];
    float* out = (float*)d_out;

    const dim3 grid(B_ * NLR / QPB);   // 1024 blocks
    const dim3 block(THREADS);
    hipLaunchKernelGGL(bignn_grouper, grid, block, 0, stream,
                       lr_idx, hr_idx, lr_feat, hr_feat, W1, b1, W2, b2, out);
}

// Round 3
// 193.341 us; speedup vs baseline: 2.1971x; 2.1971x over previous
//
#include <hip/hip_runtime.h>
#include <cstdint>
#include <cstddef>
#include <climits>

// Problem constants (fixed by the reference)
constexpr int B_   = 2;
constexpr int NLR  = 8192;
constexpr int NHR  = 16384;
constexpr int CCH  = 32;    // feature channels
constexpr int NS   = 64;    // nsample
constexpr int THREADS = 256;

// Spatial grid: hr coords span x in (0,10], y+40 in (0,10], z+3 in (0,20].
// Cell size 1.001 (SCALE = 1/1.001 ~= 0.999) >= radius + fp slack, so a
// +-1 cell window provably covers the radius-1 ball even with rounded
// binning coordinates.
constexpr int GX = 11, GY = 11, GZ = 20;
constexpr int NCELLS = GX * GY * GZ;     // 2420 per batch
constexpr int NCT    = B_ * NCELLS;      // 4840 total
constexpr int CAP    = 192;              // per-query candidate cap (expected ~34)
constexpr float SCALE = 0.999f;

// xyz = (float)i * vox + off + 0.5f*vox, all ops round-to-nearest f32,
// no fma contraction — must match the JAX/np reference bit-for-bit so the
// d2 <= 1.0 boundary test never flips.
__device__ __forceinline__ float cvt_coord(int i, float vox, float off) {
    return __fadd_rn(__fadd_rn(__fmul_rn((float)i, vox), off), __fmul_rn(0.5f, vox));
}

__device__ __forceinline__ void hr_coords(const int* ip, float& x, float& y, float& z) {
    // spconv order (z,y,x)
    x = cvt_coord(ip[2], 0.05f,   0.0f);
    y = cvt_coord(ip[1], 0.05f, -40.0f);
    z = cvt_coord(ip[0], 0.1f,   -3.0f);
}

__device__ __forceinline__ int cell_of(float x, float y, float z) {
    const int cx = (int)(__fmul_rn(x, SCALE));
    const int cy = (int)(__fmul_rn(__fadd_rn(y, 40.0f), SCALE));
    const int cz = (int)(__fmul_rn(__fadd_rn(z,  3.0f), SCALE));
    return (cz * GY + cy) * GX + cx;
}

// ---- K1: per-cell histogram ----
extern "C" __global__ void k_hist(const int* __restrict__ hr_idx, int* __restrict__ cnt) {
    const int gid = blockIdx.x * THREADS + threadIdx.x;   // [0, B_*NHR)
    const int b = gid >> 14;                              // NHR = 16384
    const int* ip = hr_idx + (size_t)gid * 3;
    float x, y, z;
    hr_coords(ip, x, y, z);
    atomicAdd(&cnt[b * NCELLS + cell_of(x, y, z)], 1);
}

// ---- K2: exclusive scan over 4840 cell counts (single block) ----
extern "C" __global__ void k_scan(const int* __restrict__ cnt, int* __restrict__ start,
                                  int* __restrict__ cursor) {
    __shared__ int sums[THREADS];
    constexpr int CH = (NCT + THREADS - 1) / THREADS;     // 19
    const int t = threadIdx.x;
    int loc[CH];
    int s = 0;
#pragma unroll
    for (int k = 0; k < CH; ++k) {
        const int i = t * CH + k;
        loc[k] = s;
        s += (i < NCT) ? cnt[i] : 0;
    }
    sums[t] = s;
    __syncthreads();
    for (int off = 1; off < THREADS; off <<= 1) {
        const int v = (t >= off) ? sums[t - off] : 0;
        __syncthreads();
        sums[t] += v;
        __syncthreads();
    }
    const int pre = (t > 0) ? sums[t - 1] : 0;
#pragma unroll
    for (int k = 0; k < CH; ++k) {
        const int i = t * CH + k;
        if (i < NCT) {
            const int st = pre + loc[k];
            start[i]  = st;
            cursor[i] = st;
        }
    }
}

// ---- K3: scatter points (xyz + packed id) into cell-sorted order ----
extern "C" __global__ void k_scatter(const int* __restrict__ hr_idx, int* __restrict__ cursor,
                                     float4* __restrict__ pts) {
    const int gid = blockIdx.x * THREADS + threadIdx.x;
    const int b = gid >> 14;
    const int i = gid & (NHR - 1);                        // local point index in batch
    const int* ip = hr_idx + (size_t)gid * 3;
    float x, y, z;
    hr_coords(ip, x, y, z);
    const int c = b * NCELLS + cell_of(x, y, z);
    const int slot = atomicAdd(&cursor[c], 1);            // order within cell irrelevant
    float4 v;
    v.x = x; v.y = y; v.z = z; v.w = __int_as_float(i);
    pts[slot] = v;
}

// ---- K4: ball query (grid) + MLP + max-pool; one wave per query ----
extern "C" __global__ void __launch_bounds__(THREADS, 2)
k_group(const int* __restrict__ lr_idx, const int* __restrict__ hr_idx,
        const float* __restrict__ lr_feat, const float* __restrict__ hr_feat,
        const float* __restrict__ W1, const float* __restrict__ b1,
        const float* __restrict__ W2, const float* __restrict__ b2,
        const int* __restrict__ start, const int* __restrict__ count,
        const float4* __restrict__ pts, float* __restrict__ out)
{
    __shared__ float4 cand[4][CAP];

    const int tid  = threadIdx.x;
    const int wave = tid >> 6;
    const int lane = tid & 63;
    const int q    = blockIdx.x * 4 + wave;               // [0, B_*NLR)
    const int b    = q >> 13;                             // NLR = 8192

    const int* qip = lr_idx + (size_t)q * 3;              // (z,y,x)
    const float qx = cvt_coord(qip[2], 0.4f,   0.0f);
    const float qy = cvt_coord(qip[1], 0.4f, -40.0f);
    const float qz = cvt_coord(qip[0], 1.0f,  -3.0f);

    const int cqx = (int)(__fmul_rn(qx, SCALE));
    const int cqy = (int)(__fmul_rn(__fadd_rn(qy, 40.0f), SCALE));
    const int cqz = (int)(__fmul_rn(__fadd_rn(qz,  3.0f), SCALE));
    const int x0 = max(cqx - 1, 0), x1 = min(cqx + 1, GX - 1);
    const int y0 = max(cqy - 1, 0), y1 = min(cqy + 1, GY - 1);
    const int z0 = max(cqz - 1, 0), z1 = min(cqz + 1, GZ - 1);

    // --- collect in-radius candidates from <=27 cells ---
    int cnt = 0;
    for (int zz = z0; zz <= z1; ++zz)
    for (int yy = y0; yy <= y1; ++yy)
    for (int xx = x0; xx <= x1; ++xx) {
        const int g = b * NCELLS + (zz * GY + yy) * GX + xx;
        const int s = start[g];
        const int L = count[g];
        for (int base = 0; base < L; base += 64) {
            const int j = base + lane;
            bool ok = false;
            float4 pv;
            if (j < L) {
                pv = pts[s + j];
                const float dx = __fsub_rn(qx, pv.x);
                const float dy = __fsub_rn(qy, pv.y);
                const float dz = __fsub_rn(qz, pv.z);
                const float d2 = __fadd_rn(__fadd_rn(__fmul_rn(dx, dx),
                                                     __fmul_rn(dy, dy)),
                                           __fmul_rn(dz, dz));
                ok = d2 <= 1.0f;
            }
            const unsigned long long m = __ballot(ok);
            if (m != 0ull) {
                const int before = (int)__popcll(m & ((1ull << lane) - 1ull));
                const int pos = cnt + before;
                if (ok && pos < CAP) cand[wave][pos] = pv;
                cnt += (int)__popcll(m);
                if (cnt > CAP) cnt = CAP;
            }
        }
    }

    // --- per-lane neighbor assignment (reference top_k-by-lowest-index semantics) ---
    int pid = 0;
    float px = 0.f, py = 0.f, pz = 0.f;
    bool have = false;

    if (cnt <= NS) {
        int mp = INT_MAX;
        if (lane < cnt) {
            const float4 v = cand[wave][lane];
            px = v.x; py = v.y; pz = v.z;
            pid = __float_as_int(v.w);
            have = true;
            mp = pid;
        }
#pragma unroll
        for (int s = 32; s >= 1; s >>= 1) mp = min(mp, __shfl_xor(mp, s, 64));
        if (lane >= cnt) pid = (cnt > 0) ? mp : 0;        // pad with first (min-index) valid; 0 if none
    } else {
        // rare: >64 in-radius -> exact 64 smallest indices by iterative extraction
        const int c = cnt;
        int mine = 0;
        for (int k = 0; k < NS; ++k) {
            int lm = INT_MAX;
            for (int j = lane; j < c; j += 64) lm = min(lm, __float_as_int(cand[wave][j].w));
#pragma unroll
            for (int s = 32; s >= 1; s >>= 1) lm = min(lm, __shfl_xor(lm, s, 64));
            for (int j = lane; j < c; j += 64)
                if (__float_as_int(cand[wave][j].w) == lm)
                    cand[wave][j].w = __int_as_float(INT_MAX);
            if (lane == k) mine = lm;
        }
        pid = mine;
    }

    if (!have) {   // padding lanes / rare path: recompute coords (exact same arithmetic)
        const int* ip = hr_idx + ((size_t)b * NHR + pid) * 3;
        hr_coords(ip, px, py, pz);
    }

    // --- MLP input: [rel_xyz (hr - lr), hr_feat] ---
    float g[3 + CCH];
    g[0] = __fsub_rn(px, qx);
    g[1] = __fsub_rn(py, qy);
    g[2] = __fsub_rn(pz, qz);
    const float4* fp = reinterpret_cast<const float4*>(hr_feat + ((size_t)b * NHR + pid) * CCH);
#pragma unroll
    for (int k = 0; k < CCH / 4; ++k) {
        const float4 v = fp[k];
        g[3 + 4 * k + 0] = v.x;
        g[3 + 4 * k + 1] = v.y;
        g[3 + 4 * k + 2] = v.z;
        g[3 + 4 * k + 3] = v.w;
    }

    // layer 1: 35 -> 32 (weights wave-uniform -> scalar loads)
    float h[32];
#pragma unroll
    for (int j = 0; j < 32; ++j) h[j] = b1[j];
#pragma unroll
    for (int k = 0; k < 35; ++k) {
        const float gk = g[k];
#pragma unroll
        for (int j = 0; j < 32; ++j)
            h[j] = fmaf(gk, W1[k * 32 + j], h[j]);
    }
#pragma unroll
    for (int j = 0; j < 32; ++j) h[j] = fmaxf(h[j], 0.0f);

    // layer 2: 32 -> 32
    float h2[32];
#pragma unroll
    for (int j = 0; j < 32; ++j) h2[j] = b2[j];
#pragma unroll
    for (int k = 0; k < 32; ++k) {
        const float hk = h[k];
#pragma unroll
        for (int j = 0; j < 32; ++j)
            h2[j] = fmaf(hk, W2[k * 32 + j], h2[j]);
    }
#pragma unroll
    for (int j = 0; j < 32; ++j) h2[j] = fmaxf(h2[j], 0.0f);

    // max over 64 neighbor slots: 6-step xor butterfly
#pragma unroll
    for (int s = 32; s >= 1; s >>= 1) {
#pragma unroll
        for (int j = 0; j < 32; ++j)
            h2[j] = fmaxf(h2[j], __shfl_xor(h2[j], s, 64));
    }

    // write: out[q] = [lr_feat(32) | pooled(32)]
    float* orow = out + (size_t)q * (2 * CCH);
    if (lane < CCH)
        orow[lane] = lr_feat[(size_t)q * CCH + lane];
    if (lane == 0) {
#pragma unroll
        for (int j = 0; j < 8; ++j) {
            float4 v;
            v.x = h2[4 * j + 0];
            v.y = h2[4 * j + 1];
            v.z = h2[4 * j + 2];
            v.w = h2[4 * j + 3];
            reinterpret_cast<float4*>(orow + CCH)[j] = v;
        }
    }
}

extern "C" void kernel_launch(void* const* d_in, const int* in_sizes, int n_in,
                              void* d_out, int out_size, void* d_ws, size_t ws_size,
                              hipStream_t stream) {
    const int*   lr_idx  = (const int*)  d_in[0];
    const int*   hr_idx  = (const int*)  d_in[1];
    const float* lr_feat = (const float*)d_in[2];
    const float* hr_feat = (const float*)d_in[3];
    const float* W1      = (const float*)d_in[4];
    const float* b1      = (const float*)d_in[5];
    const float* W2      = (const float*)d_in[6];
    const float* b2      = (const float*)d_in[7];
    float* out = (float*)d_out;

    // workspace layout (ws re-poisoned 0xAA every launch -> counts must be zeroed)
    int*    cell_count  = (int*)d_ws;                 // [NCT]
    int*    cell_start  = cell_count + NCT;           // [NCT]
    int*    cell_cursor = cell_start + NCT;           // [NCT]
    float4* pts         = (float4*)(cell_cursor + NCT); // [B_*NHR], offset 58080 B (16-aligned)

    hipMemsetAsync(cell_count, 0, NCT * sizeof(int), stream);

    const dim3 blk(THREADS);
    hipLaunchKernelGGL(k_hist,    dim3(B_ * NHR / THREADS), blk, 0, stream, hr_idx, cell_count);
    hipLaunchKernelGGL(k_scan,    dim3(1),                  blk, 0, stream, cell_count, cell_start, cell_cursor);
    hipLaunchKernelGGL(k_scatter, dim3(B_ * NHR / THREADS), blk, 0, stream, hr_idx, cell_cursor, pts);
    hipLaunchKernelGGL(k_group,   dim3(B_ * NLR / 4),       blk, 0, stream,
                       lr_idx, hr_idx, lr_feat, hr_feat, W1, b1, W2, b2,
                       cell_start, cell_count, pts, out);
}

// Round 7
// 177.334 us; speedup vs baseline: 2.3954x; 1.0903x over previous
//
#include <hip/hip_runtime.h>
#include <cstdint>
#include <cstddef>
#include <climits>

// Problem constants (fixed by the reference)
constexpr int B_   = 2;
constexpr int NLR  = 8192;
constexpr int NHR  = 16384;
constexpr int CCH  = 32;    // feature channels
constexpr int NS   = 64;    // nsample
constexpr int THREADS = 256;

// Spatial grid: hr coords span x in (0,10], y+40 in (0,10], z+3 in (0,20].
// Cell size 1.001 (SCALE = 1/1.001 ~= 0.999) >= radius + fp slack, so a
// +-1 cell window provably covers the radius-1 ball even with rounded
// binning coordinates.
constexpr int GX = 11, GY = 11, GZ = 20;
constexpr int NCELLS = GX * GY * GZ;     // 2420 per batch
constexpr int NCT    = B_ * NCELLS;      // 4840 total
constexpr int CAP    = 192;              // per-query candidate cap (expected ~34)
constexpr float SCALE = 0.999f;

// xyz = (float)i * vox + off + 0.5f*vox, all ops round-to-nearest f32,
// no fma contraction — must match the JAX/np reference bit-for-bit so the
// d2 <= 1.0 boundary test never flips.
__device__ __forceinline__ float cvt_coord(int i, float vox, float off) {
    return __fadd_rn(__fadd_rn(__fmul_rn((float)i, vox), off), __fmul_rn(0.5f, vox));
}

__device__ __forceinline__ void hr_coords(const int* ip, float& x, float& y, float& z) {
    // spconv order (z,y,x)
    x = cvt_coord(ip[2], 0.05f,   0.0f);
    y = cvt_coord(ip[1], 0.05f, -40.0f);
    z = cvt_coord(ip[0], 0.1f,   -3.0f);
}

__device__ __forceinline__ int cell_of(float x, float y, float z) {
    const int cx = (int)(__fmul_rn(x, SCALE));
    const int cy = (int)(__fmul_rn(__fadd_rn(y, 40.0f), SCALE));
    const int cz = (int)(__fmul_rn(__fadd_rn(z,  3.0f), SCALE));
    return (cz * GY + cy) * GX + cx;
}

// ---- K1: per-cell histogram ----
extern "C" __global__ void k_hist(const int* __restrict__ hr_idx, int* __restrict__ cnt) {
    const int gid = blockIdx.x * THREADS + threadIdx.x;   // [0, B_*NHR)
    const int b = gid >> 14;                              // NHR = 16384
    const int* ip = hr_idx + (size_t)gid * 3;
    float x, y, z;
    hr_coords(ip, x, y, z);
    atomicAdd(&cnt[b * NCELLS + cell_of(x, y, z)], 1);
}

// ---- K2: exclusive scan over 4840 cell counts (single block).
//      start has NCT+1 entries (total appended) so any contiguous cell run
//      [g0, g0+n) maps to the point range [start[g0], start[g0+n]). ----
extern "C" __global__ void k_scan(const int* __restrict__ cnt, int* __restrict__ start,
                                  int* __restrict__ cursor) {
    __shared__ int sums[THREADS];
    constexpr int CH = (NCT + THREADS - 1) / THREADS;     // 19
    const int t = threadIdx.x;
    int loc[CH];
    int s = 0;
#pragma unroll
    for (int k = 0; k < CH; ++k) {
        const int i = t * CH + k;
        loc[k] = s;
        s += (i < NCT) ? cnt[i] : 0;
    }
    sums[t] = s;
    __syncthreads();
    for (int off = 1; off < THREADS; off <<= 1) {
        const int v = (t >= off) ? sums[t - off] : 0;
        __syncthreads();
        sums[t] += v;
        __syncthreads();
    }
    const int pre = (t > 0) ? sums[t - 1] : 0;
#pragma unroll
    for (int k = 0; k < CH; ++k) {
        const int i = t * CH + k;
        if (i < NCT) {
            const int st = pre + loc[k];
            start[i]  = st;
            cursor[i] = st;
        }
    }
    if (t == THREADS - 1) start[NCT] = sums[THREADS - 1]; // total = B_*NHR
}

// ---- K3: scatter points (xyz + packed id) into cell-sorted order ----
extern "C" __global__ void k_scatter(const int* __restrict__ hr_idx, int* __restrict__ cursor,
                                     float4* __restrict__ pts) {
    const int gid = blockIdx.x * THREADS + threadIdx.x;
    const int b = gid >> 14;
    const int i = gid & (NHR - 1);                        // local point index in batch
    const int* ip = hr_idx + (size_t)gid * 3;
    float x, y, z;
    hr_coords(ip, x, y, z);
    const int c = b * NCELLS + cell_of(x, y, z);
    const int slot = atomicAdd(&cursor[c], 1);            // order within cell irrelevant
    float4 v;
    v.x = x; v.y = y; v.z = z; v.w = __int_as_float(i);
    pts[slot] = v;
}

// ---- K4: ball query (grid) + MLP + max-pool; one wave per query ----
// waves_per_eu(2,4): cap the compiler's occupancy target at 4 waves/SIMD so
// g[35]/h[32]/h2[32] stay in arch VGPRs (round-1 codegen: 92 VGPR, no
// AGPR shuffling). Round-3's 36-VGPR allocation tripled MLP VALU work.
extern "C" __global__ void __launch_bounds__(THREADS)
__attribute__((amdgpu_waves_per_eu(2, 4)))
k_group(const int* __restrict__ lr_idx, const int* __restrict__ hr_idx,
        const float* __restrict__ lr_feat, const float* __restrict__ hr_feat,
        const float* __restrict__ W1, const float* __restrict__ b1,
        const float* __restrict__ W2, const float* __restrict__ b2,
        const int* __restrict__ start, const float4* __restrict__ pts,
        float* __restrict__ out)
{
    __shared__ int cand[4][CAP];          // candidate original ids, per wave

    const int tid  = threadIdx.x;
    const int wave = tid >> 6;
    const int lane = tid & 63;
    const int q    = blockIdx.x * 4 + wave;               // [0, B_*NLR)
    const int b    = q >> 13;                             // NLR = 8192

    const int* qip = lr_idx + (size_t)q * 3;              // (z,y,x)
    const float qx = cvt_coord(qip[2], 0.4f,   0.0f);
    const float qy = cvt_coord(qip[1], 0.4f, -40.0f);
    const float qz = cvt_coord(qip[0], 1.0f,  -3.0f);

    const int cqx = (int)(__fmul_rn(qx, SCALE));
    const int cqy = (int)(__fmul_rn(__fadd_rn(qy, 40.0f), SCALE));
    const int cqz = (int)(__fmul_rn(__fadd_rn(qz,  3.0f), SCALE));
    const int x0 = max(cqx - 1, 0), x1 = min(cqx + 1, GX - 1);
    const int y0 = max(cqy - 1, 0), y1 = min(cqy + 1, GY - 1);
    const int z0 = max(cqz - 1, 0), z1 = min(cqz + 1, GZ - 1);
    const int nx = x1 - x0 + 1;
    const int bbase = b * NCELLS;

    // --- collect in-radius candidate ids. x-adjacent cells are contiguous
    //     in cell-id order and start[] is cumulative, so each (z,y) row of
    //     nx cells is ONE contiguous pts range: <=9 ranges instead of 27
    //     cell-sized fragments. Order of collection is irrelevant (max-pool
    //     is order-invariant; padding uses min id; >NS path re-sorts). ---
    int cnt = 0;
    for (int zz = z0; zz <= z1; ++zz)
    for (int yy = y0; yy <= y1; ++yy) {
        const int g0 = bbase + (zz * GY + yy) * GX + x0;
        const int s  = start[g0];
        const int e  = start[g0 + nx];
        for (int base = s; base < e; base += 64) {
            const int j = base + lane;
            bool ok = false;
            int id = 0;
            if (j < e) {
                const float4 pv = pts[j];
                const float dx = __fsub_rn(qx, pv.x);
                const float dy = __fsub_rn(qy, pv.y);
                const float dz = __fsub_rn(qz, pv.z);
                const float d2 = __fadd_rn(__fadd_rn(__fmul_rn(dx, dx),
                                                     __fmul_rn(dy, dy)),
                                           __fmul_rn(dz, dz));
                ok = d2 <= 1.0f;
                id = __float_as_int(pv.w);
            }
            const unsigned long long m = __ballot(ok);
            if (m != 0ull) {
                const int before = (int)__popcll(m & ((1ull << lane) - 1ull));
                const int pos = cnt + before;
                if (ok && pos < CAP) cand[wave][pos] = id;
                cnt += (int)__popcll(m);
                if (cnt > CAP) cnt = CAP;
            }
        }
    }

    // --- per-lane neighbor assignment (reference top_k-by-lowest-index) ---
    int pid;
    if (cnt <= NS) {
        int myid = (lane < cnt) ? cand[wave][lane] : INT_MAX;
        int mp = myid;
#pragma unroll
        for (int s = 32; s >= 1; s >>= 1) mp = min(mp, __shfl_xor(mp, s, 64));
        // lanes < cnt keep their id; others pad with min id (0 if none)
        pid = (lane < cnt) ? myid : ((cnt > 0) ? mp : 0);
    } else {
        // rare: >64 in-radius -> exact 64 smallest ids by iterative extraction
        const int c = cnt;
        int mine = 0;
        for (int k = 0; k < NS; ++k) {
            int lm = INT_MAX;
            for (int j = lane; j < c; j += 64) lm = min(lm, cand[wave][j]);
#pragma unroll
            for (int s = 32; s >= 1; s >>= 1) lm = min(lm, __shfl_xor(lm, s, 64));
            for (int j = lane; j < c; j += 64)
                if (cand[wave][j] == lm) cand[wave][j] = INT_MAX;
            if (lane == k) mine = lm;
        }
        pid = mine;
    }

    // --- uniform path for ALL lanes: coords from hr_idx (exact arithmetic) ---
    const int* ip = hr_idx + ((size_t)b * NHR + pid) * 3;
    float px, py, pz;
    hr_coords(ip, px, py, pz);

    // --- MLP input: [rel_xyz (hr - lr), hr_feat] ---
    float g[3 + CCH];
    g[0] = __fsub_rn(px, qx);
    g[1] = __fsub_rn(py, qy);
    g[2] = __fsub_rn(pz, qz);
    const float4* fp = reinterpret_cast<const float4*>(hr_feat + ((size_t)b * NHR + pid) * CCH);
#pragma unroll
    for (int k = 0; k < CCH / 4; ++k) {
        const float4 v = fp[k];
        g[3 + 4 * k + 0] = v.x;
        g[3 + 4 * k + 1] = v.y;
        g[3 + 4 * k + 2] = v.z;
        g[3 + 4 * k + 3] = v.w;
    }

    // layer 1: 35 -> 32 (weights wave-uniform -> scalar loads)
    float h[32];
#pragma unroll 32
    for (int j = 0; j < 32; ++j) h[j] = b1[j];
#pragma unroll 35
    for (int k = 0; k < 35; ++k) {
        const float gk = g[k];
#pragma unroll 32
        for (int j = 0; j < 32; ++j)
            h[j] = fmaf(gk, W1[k * 32 + j], h[j]);
    }
#pragma unroll 32
    for (int j = 0; j < 32; ++j) h[j] = fmaxf(h[j], 0.0f);

    // layer 2: 32 -> 32
    float h2[32];
#pragma unroll 32
    for (int j = 0; j < 32; ++j) h2[j] = b2[j];
#pragma unroll 32
    for (int k = 0; k < 32; ++k) {
        const float hk = h[k];
#pragma unroll 32
        for (int j = 0; j < 32; ++j)
            h2[j] = fmaf(hk, W2[k * 32 + j], h2[j]);
    }
#pragma unroll 32
    for (int j = 0; j < 32; ++j) h2[j] = fmaxf(h2[j], 0.0f);

    // max over 64 neighbor slots: 6-step xor butterfly
#pragma unroll
    for (int s = 32; s >= 1; s >>= 1) {
#pragma unroll 32
        for (int j = 0; j < 32; ++j)
            h2[j] = fmaxf(h2[j], __shfl_xor(h2[j], s, 64));
    }

    // write: out[q] = [lr_feat(32) | pooled(32)]
    float* orow = out + (size_t)q * (2 * CCH);
    if (lane < CCH)
        orow[lane] = lr_feat[(size_t)q * CCH + lane];
    if (lane == 0) {
#pragma unroll
        for (int j = 0; j < 8; ++j) {
            float4 v;
            v.x = h2[4 * j + 0];
            v.y = h2[4 * j + 1];
            v.z = h2[4 * j + 2];
            v.w = h2[4 * j + 3];
            reinterpret_cast<float4*>(orow + CCH)[j] = v;
        }
    }
}

extern "C" void kernel_launch(void* const* d_in, const int* in_sizes, int n_in,
                              void* d_out, int out_size, void* d_ws, size_t ws_size,
                              hipStream_t stream) {
    const int*   lr_idx  = (const int*)  d_in[0];
    const int*   hr_idx  = (const int*)  d_in[1];
    const float* lr_feat = (const float*)d_in[2];
    const float* hr_feat = (const float*)d_in[3];
    const float* W1      = (const float*)d_in[4];
    const float* b1      = (const float*)d_in[5];
    const float* W2      = (const float*)d_in[6];
    const float* b2      = (const float*)d_in[7];
    float* out = (float*)d_out;

    // workspace layout (ws re-poisoned 0xAA every launch -> counts must be zeroed)
    int*    cell_count  = (int*)d_ws;                     // [NCT]
    int*    cell_start  = cell_count + NCT;               // [NCT+1]
    int*    cell_cursor = cell_start + (NCT + 1);         // [NCT]
    // pad to 16B for float4
    size_t  off = ((size_t)(3 * NCT + 1) * sizeof(int) + 15) & ~(size_t)15;
    float4* pts = (float4*)((char*)d_ws + off);           // [B_*NHR]

    hipMemsetAsync(cell_count, 0, NCT * sizeof(int), stream);

    const dim3 blk(THREADS);
    hipLaunchKernelGGL(k_hist,    dim3(B_ * NHR / THREADS), blk, 0, stream, hr_idx, cell_count);
    hipLaunchKernelGGL(k_scan,    dim3(1),                  blk, 0, stream, cell_count, cell_start, cell_cursor);
    hipLaunchKernelGGL(k_scatter, dim3(B_ * NHR / THREADS), blk, 0, stream, hr_idx, cell_cursor, pts);
    hipLaunchKernelGGL(k_group,   dim3(B_ * NLR / 4),       blk, 0, stream,
                       lr_idx, hr_idx, lr_feat, hr_feat, W1, b1, W2, b2,
                       cell_start, pts, out);
}

// Round 8
// 149.455 us; speedup vs baseline: 2.8422x; 1.1865x over previous
//
#include <hip/hip_runtime.h>
#include <hip/hip_bf16.h>
#include <cstdint>
#include <cstddef>
#include <climits>

// Problem constants (fixed by the reference)
constexpr int B_   = 2;
constexpr int NLR  = 8192;
constexpr int NHR  = 16384;
constexpr int CCH  = 32;    // feature channels
constexpr int NS   = 64;    // nsample
constexpr int THREADS = 256;

// Spatial grid: hr coords span x in (0,10], y+40 in (0,10], z+3 in (0,20].
constexpr int GX = 11, GY = 11, GZ = 20;
constexpr int NCELLS = GX * GY * GZ;     // 2420 per batch
constexpr int NCT    = B_ * NCELLS;      // 4840 total
constexpr int CAP    = 192;              // per-query candidate cap (expected ~34)
constexpr float SCALE = 0.999f;

typedef __attribute__((ext_vector_type(8))) short bf16x8;
typedef __attribute__((ext_vector_type(4))) float f32x4;

// xyz = (float)i * vox + off + 0.5f*vox, all ops round-to-nearest f32 —
// must match the JAX/np reference bit-for-bit so d2 <= 1.0 never flips.
__device__ __forceinline__ float cvt_coord(int i, float vox, float off) {
    return __fadd_rn(__fadd_rn(__fmul_rn((float)i, vox), off), __fmul_rn(0.5f, vox));
}

__device__ __forceinline__ void hr_coords(const int* ip, float& x, float& y, float& z) {
    x = cvt_coord(ip[2], 0.05f,   0.0f);
    y = cvt_coord(ip[1], 0.05f, -40.0f);
    z = cvt_coord(ip[0], 0.1f,   -3.0f);
}

__device__ __forceinline__ int cell_of(float x, float y, float z) {
    const int cx = (int)(__fmul_rn(x, SCALE));
    const int cy = (int)(__fmul_rn(__fadd_rn(y, 40.0f), SCALE));
    const int cz = (int)(__fmul_rn(__fadd_rn(z,  3.0f), SCALE));
    return (cz * GY + cy) * GX + cx;
}

__device__ __forceinline__ unsigned short f2bf(float f) {
    __hip_bfloat16 h = __float2bfloat16(f);
    return __builtin_bit_cast(unsigned short, h);
}

// ---- K1: per-cell histogram ----
extern "C" __global__ void k_hist(const int* __restrict__ hr_idx, int* __restrict__ cnt) {
    const int gid = blockIdx.x * THREADS + threadIdx.x;
    const int b = gid >> 14;
    const int* ip = hr_idx + (size_t)gid * 3;
    float x, y, z;
    hr_coords(ip, x, y, z);
    atomicAdd(&cnt[b * NCELLS + cell_of(x, y, z)], 1);
}

// ---- K2: exclusive scan over cell counts (single block); start[NCT]=total ----
extern "C" __global__ void k_scan(const int* __restrict__ cnt, int* __restrict__ start,
                                  int* __restrict__ cursor) {
    __shared__ int sums[THREADS];
    constexpr int CH = (NCT + THREADS - 1) / THREADS;     // 19
    const int t = threadIdx.x;
    int loc[CH];
    int s = 0;
#pragma unroll
    for (int k = 0; k < CH; ++k) {
        const int i = t * CH + k;
        loc[k] = s;
        s += (i < NCT) ? cnt[i] : 0;
    }
    sums[t] = s;
    __syncthreads();
    for (int off = 1; off < THREADS; off <<= 1) {
        const int v = (t >= off) ? sums[t - off] : 0;
        __syncthreads();
        sums[t] += v;
        __syncthreads();
    }
    const int pre = (t > 0) ? sums[t - 1] : 0;
#pragma unroll
    for (int k = 0; k < CH; ++k) {
        const int i = t * CH + k;
        if (i < NCT) {
            const int st = pre + loc[k];
            start[i]  = st;
            cursor[i] = st;
        }
    }
    if (t == THREADS - 1) start[NCT] = sums[THREADS - 1];
}

// ---- K3: scatter points (xyz + packed id) into cell-sorted order ----
extern "C" __global__ void k_scatter(const int* __restrict__ hr_idx, int* __restrict__ cursor,
                                     float4* __restrict__ pts) {
    const int gid = blockIdx.x * THREADS + threadIdx.x;
    const int b = gid >> 14;
    const int i = gid & (NHR - 1);
    const int* ip = hr_idx + (size_t)gid * 3;
    float x, y, z;
    hr_coords(ip, x, y, z);
    const int c = b * NCELLS + cell_of(x, y, z);
    const int slot = atomicAdd(&cursor[c], 1);
    float4 v;
    v.x = x; v.y = y; v.z = z; v.w = __int_as_float(i);
    pts[slot] = v;
}

// ---- K4: ball query (grid) + MFMA MLP + max-pool; one wave per query ----
// Round-8 change: replace the per-lane fp32 MLP (measured 2.1x VALU bloat at
// 52 VGPR, r7) with mfma_f32_16x16x32_bf16. Per query: H[64][32] =
// X[64][35]*W1 (16 MFMA, K padded to 64 with xyz in k=32..34), H2 = Hb*W2
// (8 MFMA). Accumulate in AGPRs -> no register juggling. LDS rows are
// XOR-swizzled (byte ^= (row&3)<<4) to break the stride-64B bank conflict
// on ds_read_b128 fragment loads (G4).
extern "C" __global__ void __launch_bounds__(THREADS)
k_group(const int* __restrict__ lr_idx, const int* __restrict__ hr_idx,
        const float* __restrict__ lr_feat, const float* __restrict__ hr_feat,
        const float* __restrict__ W1, const float* __restrict__ b1,
        const float* __restrict__ W2, const float* __restrict__ b2,
        const int* __restrict__ start, const float4* __restrict__ pts,
        float* __restrict__ out)
{
    // block-shared pre-built B-fragments (weights), built once, synced once
    __shared__ __align__(16) unsigned short W1f[2][2][64][8]; // [ks][ct][lane][j]
    __shared__ __align__(16) unsigned short W2f[2][64][8];    // [ct][lane][j]
    // per-wave staging
    __shared__ __align__(16) unsigned short Xf[4][64][32];    // neighbor feats bf16, swizzled rows
    __shared__ __align__(16) unsigned short XYZ[4][64][4];    // rel xyz bf16 (+pad)
    __shared__ __align__(16) unsigned short Hb[4][64][32];    // layer-1 out bf16, swizzled rows
    __shared__ int cand[4][CAP];

    const int tid  = threadIdx.x;
    const int wave = tid >> 6;
    const int lane = tid & 63;
    const int q    = blockIdx.x * 4 + wave;
    const int b    = q >> 13;

    // --- cooperative W-fragment build (logical k': 0..31 = feats = ref k+3;
    //     32..34 = xyz = ref k-32; >=35 = zero) ---
#pragma unroll
    for (int e = 0; e < 8; ++e) {
        const int flat = tid * 8 + e;                 // [0, 2048)
        const int j  = flat & 7;
        const int l  = (flat >> 3) & 63;
        const int ct = (flat >> 9) & 1;
        const int ks = (flat >> 10) & 1;
        const int kp = ks * 32 + (l >> 4) * 8 + j;    // logical k'
        const int n  = ct * 16 + (l & 15);
        float v = 0.0f;
        if (kp < 32)       v = W1[(kp + 3) * 32 + n];
        else if (kp < 35)  v = W1[(kp - 32) * 32 + n];
        W1f[ks][ct][l][j] = f2bf(v);
    }
#pragma unroll
    for (int e = 0; e < 4; ++e) {
        const int flat = tid * 4 + e;                 // [0, 1024)
        const int j  = flat & 7;
        const int l  = (flat >> 3) & 63;
        const int ct = (flat >> 9) & 1;
        const int k  = (l >> 4) * 8 + j;
        const int n  = ct * 16 + (l & 15);
        W2f[ct][l][j] = f2bf(W2[k * 32 + n]);
    }
    __syncthreads();   // only block-wide barrier; everything after is per-wave

    // --- query center ---
    const int* qip = lr_idx + (size_t)q * 3;
    const float qx = cvt_coord(qip[2], 0.4f,   0.0f);
    const float qy = cvt_coord(qip[1], 0.4f, -40.0f);
    const float qz = cvt_coord(qip[0], 1.0f,  -3.0f);

    const int cqx = (int)(__fmul_rn(qx, SCALE));
    const int cqy = (int)(__fmul_rn(__fadd_rn(qy, 40.0f), SCALE));
    const int cqz = (int)(__fmul_rn(__fadd_rn(qz,  3.0f), SCALE));
    const int x0 = max(cqx - 1, 0), x1 = min(cqx + 1, GX - 1);
    const int y0 = max(cqy - 1, 0), y1 = min(cqy + 1, GY - 1);
    const int z0 = max(cqz - 1, 0), z1 = min(cqz + 1, GZ - 1);
    const int nx = x1 - x0 + 1;
    const int bbase = b * NCELLS;

    // --- collect in-radius candidate ids (row-merged ranges; verified r3/r7) ---
    int cnt = 0;
    for (int zz = z0; zz <= z1; ++zz)
    for (int yy = y0; yy <= y1; ++yy) {
        const int g0 = bbase + (zz * GY + yy) * GX + x0;
        const int s  = start[g0];
        const int e  = start[g0 + nx];
        for (int base = s; base < e; base += 64) {
            const int j = base + lane;
            bool ok = false;
            int id = 0;
            if (j < e) {
                const float4 pv = pts[j];
                const float dx = __fsub_rn(qx, pv.x);
                const float dy = __fsub_rn(qy, pv.y);
                const float dz = __fsub_rn(qz, pv.z);
                const float d2 = __fadd_rn(__fadd_rn(__fmul_rn(dx, dx),
                                                     __fmul_rn(dy, dy)),
                                           __fmul_rn(dz, dz));
                ok = d2 <= 1.0f;
                id = __float_as_int(pv.w);
            }
            const unsigned long long m = __ballot(ok);
            if (m != 0ull) {
                const int before = (int)__popcll(m & ((1ull << lane) - 1ull));
                const int pos = cnt + before;
                if (ok && pos < CAP) cand[wave][pos] = id;
                cnt += (int)__popcll(m);
                if (cnt > CAP) cnt = CAP;
            }
        }
    }

    // --- per-lane neighbor assignment (reference top_k-by-lowest-index) ---
    int pid;
    if (cnt <= NS) {
        int myid = (lane < cnt) ? cand[wave][lane] : INT_MAX;
        int mp = myid;
#pragma unroll
        for (int s = 32; s >= 1; s >>= 1) mp = min(mp, __shfl_xor(mp, s, 64));
        pid = (lane < cnt) ? myid : ((cnt > 0) ? mp : 0);
    } else {
        const int c = cnt;
        int mine = 0;
        for (int k = 0; k < NS; ++k) {
            int lm = INT_MAX;
            for (int j = lane; j < c; j += 64) lm = min(lm, cand[wave][j]);
#pragma unroll
            for (int s = 32; s >= 1; s >>= 1) lm = min(lm, __shfl_xor(lm, s, 64));
            for (int j = lane; j < c; j += 64)
                if (cand[wave][j] == lm) cand[wave][j] = INT_MAX;
            if (lane == k) mine = lm;
        }
        pid = mine;
    }

    // --- gather neighbor row `lane` and stage to LDS (bf16) ---
    {
        const int* ip = hr_idx + ((size_t)b * NHR + pid) * 3;
        float px, py, pz;
        hr_coords(ip, px, py, pz);
        const int r = lane;
        // rel xyz (f32 exact sub, then bf16)
        ushort4 t;
        t.x = f2bf(__fsub_rn(px, qx));
        t.y = f2bf(__fsub_rn(py, qy));
        t.z = f2bf(__fsub_rn(pz, qz));
        t.w = 0;
        *reinterpret_cast<ushort4*>(&XYZ[wave][r][0]) = t;
        // 32 feats -> 4 swizzled 16B chunks
        const float4* fp = reinterpret_cast<const float4*>(hr_feat + ((size_t)b * NHR + pid) * CCH);
#pragma unroll
        for (int c = 0; c < 4; ++c) {
            const float4 a = fp[2 * c];
            const float4 d = fp[2 * c + 1];
            uint4 u;
            u.x = (unsigned)f2bf(a.x) | ((unsigned)f2bf(a.y) << 16);
            u.y = (unsigned)f2bf(a.z) | ((unsigned)f2bf(a.w) << 16);
            u.z = (unsigned)f2bf(d.x) | ((unsigned)f2bf(d.y) << 16);
            u.w = (unsigned)f2bf(d.z) | ((unsigned)f2bf(d.w) << 16);
            const int byteoff = (c * 16) ^ ((r & 3) << 4);
            *reinterpret_cast<uint4*>(reinterpret_cast<char*>(&Xf[wave][r][0]) + byteoff) = u;
        }
    }
    // same-wave LDS ordering: all 64 rows written by this wave's own lanes;
    // ds ops are in-order per wave, compiler inserts lgkmcnt before reads.

    const int hi  = lane >> 4;
    const int c15 = lane & 15;

    // --- layer 1: H[64][32] = X[64][64] * W1p[64][32], 16 MFMA ---
    bf16x8 B1[2][2];
#pragma unroll
    for (int ks = 0; ks < 2; ++ks)
#pragma unroll
        for (int ct = 0; ct < 2; ++ct)
            B1[ks][ct] = *reinterpret_cast<const bf16x8*>(&W1f[ks][ct][lane][0]);

    const f32x4 zero4 = {0.0f, 0.0f, 0.0f, 0.0f};
    f32x4 acc[4][2];
#pragma unroll
    for (int rt = 0; rt < 4; ++rt) { acc[rt][0] = zero4; acc[rt][1] = zero4; }

#pragma unroll
    for (int rt = 0; rt < 4; ++rt) {
        const int row = rt * 16 + c15;
        const int byteoff = (hi * 16) ^ ((row & 3) << 4);
        const bf16x8 a0 = *reinterpret_cast<const bf16x8*>(
            reinterpret_cast<const char*>(&Xf[wave][row][0]) + byteoff);
        bf16x8 a1 = {0, 0, 0, 0, 0, 0, 0, 0};
        if (hi == 0) {
            const ushort4 t = *reinterpret_cast<const ushort4*>(&XYZ[wave][row][0]);
            a1[0] = (short)t.x; a1[1] = (short)t.y; a1[2] = (short)t.z;
        }
#pragma unroll
        for (int ct = 0; ct < 2; ++ct) {
            acc[rt][ct] = __builtin_amdgcn_mfma_f32_16x16x32_bf16(a0, B1[0][ct], acc[rt][ct], 0, 0, 0);
            acc[rt][ct] = __builtin_amdgcn_mfma_f32_16x16x32_bf16(a1, B1[1][ct], acc[rt][ct], 0, 0, 0);
        }
    }

    // --- bias + relu + restage Hb (bf16, swizzled) ---
    const float bias1_0 = b1[c15];
    const float bias1_1 = b1[16 + c15];
#pragma unroll
    for (int rt = 0; rt < 4; ++rt)
#pragma unroll
        for (int ct = 0; ct < 2; ++ct) {
            const float bb = ct ? bias1_1 : bias1_0;
#pragma unroll
            for (int rr = 0; rr < 4; ++rr) {
                const float v = fmaxf(acc[rt][ct][rr] + bb, 0.0f);
                const int row = rt * 16 + hi * 4 + rr;
                const int boff = (ct * 32 + c15 * 2) ^ ((row & 3) << 4);
                *reinterpret_cast<unsigned short*>(
                    reinterpret_cast<char*>(&Hb[wave][row][0]) + boff) = f2bf(v);
            }
        }

    // --- layer 2: H2[64][32] = Hb[64][32] * W2[32][32], 8 MFMA ---
    bf16x8 B2[2];
#pragma unroll
    for (int ct = 0; ct < 2; ++ct)
        B2[ct] = *reinterpret_cast<const bf16x8*>(&W2f[ct][lane][0]);

    f32x4 acc2[4][2];
#pragma unroll
    for (int rt = 0; rt < 4; ++rt) { acc2[rt][0] = zero4; acc2[rt][1] = zero4; }

#pragma unroll
    for (int rt = 0; rt < 4; ++rt) {
        const int row = rt * 16 + c15;
        const int byteoff = (hi * 16) ^ ((row & 3) << 4);
        const bf16x8 a = *reinterpret_cast<const bf16x8*>(
            reinterpret_cast<const char*>(&Hb[wave][row][0]) + byteoff);
#pragma unroll
        for (int ct = 0; ct < 2; ++ct)
            acc2[rt][ct] = __builtin_amdgcn_mfma_f32_16x16x32_bf16(a, B2[ct], acc2[rt][ct], 0, 0, 0);
    }

    // --- bias + relu + max-pool over 64 rows ---
    const float bias2_0 = b2[c15];
    const float bias2_1 = b2[16 + c15];
    float m0 = 0.0f, m1 = 0.0f;    // relu output >= 0, pool over all 64 rows
#pragma unroll
    for (int rt = 0; rt < 4; ++rt)
#pragma unroll
        for (int rr = 0; rr < 4; ++rr) {
            m0 = fmaxf(m0, fmaxf(acc2[rt][0][rr] + bias2_0, 0.0f));
            m1 = fmaxf(m1, fmaxf(acc2[rt][1][rr] + bias2_1, 0.0f));
        }
    // reduce over hi groups (lane bits 4,5)
    m0 = fmaxf(m0, __shfl_xor(m0, 16, 64));
    m0 = fmaxf(m0, __shfl_xor(m0, 32, 64));
    m1 = fmaxf(m1, __shfl_xor(m1, 16, 64));
    m1 = fmaxf(m1, __shfl_xor(m1, 32, 64));

    // --- write: out[q] = [lr_feat(32) | pooled(32)] ---
    float* orow = out + (size_t)q * (2 * CCH);
    if (lane < CCH)
        orow[lane] = lr_feat[(size_t)q * CCH + lane];
    if (lane < 16) {
        orow[CCH + lane]      = m0;
        orow[CCH + 16 + lane] = m1;
    }
}

extern "C" void kernel_launch(void* const* d_in, const int* in_sizes, int n_in,
                              void* d_out, int out_size, void* d_ws, size_t ws_size,
                              hipStream_t stream) {
    const int*   lr_idx  = (const int*)  d_in[0];
    const int*   hr_idx  = (const int*)  d_in[1];
    const float* lr_feat = (const float*)d_in[2];
    const float* hr_feat = (const float*)d_in[3];
    const float* W1      = (const float*)d_in[4];
    const float* b1      = (const float*)d_in[5];
    const float* W2      = (const float*)d_in[6];
    const float* b2      = (const float*)d_in[7];
    float* out = (float*)d_out;

    // workspace layout (ws re-poisoned 0xAA every launch -> counts must be zeroed)
    int*    cell_count  = (int*)d_ws;                     // [NCT]
    int*    cell_start  = cell_count + NCT;               // [NCT+1]
    int*    cell_cursor = cell_start + (NCT + 1);         // [NCT]
    size_t  off = ((size_t)(3 * NCT + 1) * sizeof(int) + 15) & ~(size_t)15;
    float4* pts = (float4*)((char*)d_ws + off);           // [B_*NHR]

    hipMemsetAsync(cell_count, 0, NCT * sizeof(int), stream);

    const dim3 blk(THREADS);
    hipLaunchKernelGGL(k_hist,    dim3(B_ * NHR / THREADS), blk, 0, stream, hr_idx, cell_count);
    hipLaunchKernelGGL(k_scan,    dim3(1),                  blk, 0, stream, cell_count, cell_start, cell_cursor);
    hipLaunchKernelGGL(k_scatter, dim3(B_ * NHR / THREADS), blk, 0, stream, hr_idx, cell_cursor, pts);
    hipLaunchKernelGGL(k_group,   dim3(B_ * NLR / 4),       blk, 0, stream,
                       lr_idx, hr_idx, lr_feat, hr_feat, W1, b1, W2, b2,
                       cell_start, pts, out);
}